// Round 16
// baseline (661.750 us; speedup 1.0000x reference)
//
#include <hip/hip_runtime.h>
#include <stdint.h>

typedef __attribute__((ext_vector_type(8))) short short8_t;
typedef __attribute__((ext_vector_type(4))) float f32x4;

__device__ __forceinline__ short f2bf(float f) {
  union { float f; uint32_t u; } v; v.f = f;
  uint32_t r = v.u + 0x7FFFu + ((v.u >> 16) & 1u);
  return (short)(r >> 16);
}
__device__ __forceinline__ float bf2f(short s) {
  union { uint32_t u; float f; } v; v.u = ((uint32_t)(uint16_t)s) << 16; return v.f;
}
__device__ __forceinline__ void gld16(const void* g, void* l) {
  __builtin_amdgcn_global_load_lds((const __attribute__((address_space(1))) void*)g,
                                   (__attribute__((address_space(3))) void*)l, 16, 0, 0);
}

// ---------------- fused f32 -> bf16 convert of x, Wqkv, Wout ----------------
__global__ __launch_bounds__(256) void conv3_kernel(const float* __restrict__ x,
                                                    const float* __restrict__ wqkv,
                                                    const float* __restrict__ wout,
                                                    short* __restrict__ xb,
                                                    short* __restrict__ wqb,
                                                    short* __restrict__ woutb) {
  int i = blockIdx.x * 256 + threadIdx.x;
  const int stride = gridDim.x * 256;
  for (; i < 8388608; i += stride) {
    const float4* src;
    short4* dst;
    int j;
    if (i < 4194304) { src = (const float4*)x; dst = (short4*)xb; j = i; }
    else if (i < 7340032) { src = (const float4*)wqkv; dst = (short4*)wqb; j = i - 4194304; }
    else { src = (const float4*)wout; dst = (short4*)woutb; j = i - 7340032; }
    float4 v = src[j];
    short4 o;
    o.x = f2bf(v.x); o.y = f2bf(v.y); o.z = f2bf(v.z); o.w = f2bf(v.w);
    dst[j] = o;
  }
}

// ======== 256x256 GEMM, B-IN-REGISTERS: C[M,N] = A[M,K] * B[N,K]^T ========
// LDS-traffic cut: B never touches LDS. Each wave loads its 8 B-frags (16B/lane,
// same per-lane pattern the old LDS read produced) straight from global (L2-hot via
// XCD super-tiling) one K-tile ahead into registers; compiler handles the waits.
// LDS = A only (64 KB dbuf, fragment-major, conflict-free lane-consecutive reads).
// Per-CU LDS traffic/K-tile: 256 KB -> 160 KB (-37%). Per tile: stage A(T+1) +
// load B(T+1) at top, 4 groups of {4 ds_read -> lgkmcnt(0) -> 16 MFMA}, barrier.
__device__ __forceinline__ void storeC(float* C, size_t i, float v) { C[i] = v; }
__device__ __forceinline__ void storeC(short* C, size_t i, float v) { C[i] = f2bf(v); }

template <typename OT, bool FUSEV>
__global__ __launch_bounds__(512, 2) void gemmrb(const short* __restrict__ A,
                                                 const short* __restrict__ B,
                                                 OT* __restrict__ C,
                                                 short* __restrict__ VT,
                                                 int M, int N, int K) {
  __shared__ __align__(16) short lds[32768];  // 65536 B: A frags, 2 buf x 2 ks x 16 KB
  const int tid = threadIdx.x, lane = tid & 63, w = tid >> 6;
  const int wr = w >> 2, wc = w & 3;
  const int c = lane & 15, g4 = lane >> 4;
  // XCD-clustered L2 super-tiling (8bx x 4by concurrent per XCD)
  const int xcd = (int)blockIdx.x & 7;
  const int t = (int)blockIdx.x >> 3;
  const int bx = (t & 7) + 8 * (t >> 5);
  const int by = xcd * 4 + ((t >> 3) & 3);
  const size_t m0 = (size_t)by * 256, n0 = (size_t)bx * 256;
  const size_t Kb = (size_t)K * 2;
  const char* Ab = (const char*)A + m0 * Kb;
  // A staging sources: chunk i stages frag blk = i*8 + w (row blk*16+c, byte g4*16)
  const char* aq[2];
#pragma unroll
  for (int i = 0; i < 2; ++i) aq[i] = Ab + (size_t)((i * 8 + w) * 16 + c) * Kb + g4 * 16;
  // B per-lane register-load base: lane holds B[wc*64 + n*16 + c][g4*16 ..+16]
  const char* bp = (const char*)B + (n0 + wc * 64 + c) * Kb + g4 * 16;
  char* alds = (char*)lds;
  const int aoff = wr * 8192 + lane * 16;  // + buf*32768 + ks*16384 + (mq*4+mi)*1024
  f32x4 acc[8][4] = {};
  const int NT = K >> 6, NIT = NT >> 1;

  short8_t af[4];
  short8_t breg[2][4][2];  // [set][n][ks], double-buffered across K-tiles

#define STAGEA(BUF, KS, TOFF)                                                          \
  gld16(aq[0] + (TOFF) + (KS) * 64, alds + (BUF) * 32768 + (KS) * 16384 + (w << 10));  \
  gld16(aq[1] + (TOFF) + (KS) * 64, alds + (BUF) * 32768 + (KS) * 16384 + ((8 + w) << 10))

#define LOADB(S, TT)                                                                   \
  _Pragma("unroll") for (int n = 0; n < 4; ++n)                                        \
    _Pragma("unroll") for (int ks = 0; ks < 2; ++ks)                                   \
      breg[S][n][ks] =                                                                 \
          *(const short8_t*)(bp + (size_t)n * 16 * Kb + (TT) * 128 + ks * 64)

#define RD_A(mi, OFF) \
  asm volatile("ds_read_b128 %0, %1 offset:%c2" : "=v"(af[mi]) : "v"(aoff), "i"(OFF))

#define GRP(BUF, S, MQ, KS)                                                            \
  RD_A(0, (BUF) * 32768 + (KS) * 16384 + ((MQ) * 4 + 0) * 1024);                       \
  RD_A(1, (BUF) * 32768 + (KS) * 16384 + ((MQ) * 4 + 1) * 1024);                       \
  RD_A(2, (BUF) * 32768 + (KS) * 16384 + ((MQ) * 4 + 2) * 1024);                       \
  RD_A(3, (BUF) * 32768 + (KS) * 16384 + ((MQ) * 4 + 3) * 1024);                       \
  asm volatile("s_waitcnt lgkmcnt(0)" ::: "memory");                                   \
  __builtin_amdgcn_sched_barrier(0);                                                   \
  __builtin_amdgcn_s_setprio(1);                                                       \
  _Pragma("unroll") for (int mi = 0; mi < 4; ++mi)                                     \
    _Pragma("unroll") for (int n = 0; n < 4; ++n)                                      \
      acc[(MQ) * 4 + mi][n] = __builtin_amdgcn_mfma_f32_16x16x32_bf16(                 \
          af[mi], breg[S][n][KS], acc[(MQ) * 4 + mi][n], 0, 0, 0);                     \
  __builtin_amdgcn_s_setprio(0)

#define TILE(BUF, S) \
  GRP(BUF, S, 0, 0); \
  GRP(BUF, S, 0, 1); \
  GRP(BUF, S, 1, 0); \
  GRP(BUF, S, 1, 1)

  // prologue: stage A tile0 into buf0; load B tile0 into set0
  STAGEA(0, 0, 0);
  STAGEA(0, 1, 0);
  LOADB(0, 0);
  __syncthreads();

  for (int it = 0; it < NIT; ++it) {
    const int T = it << 1;
    const int t1 = T + 1;
    const int t2 = (T + 2 < NT) ? T + 2 : NT - 1;  // tail: dead restage, unread
    // tile T (buf0/set0); prefetch tile T+1 into buf1/set1
    STAGEA(1, 0, t1 * 128);
    STAGEA(1, 1, t1 * 128);
    LOADB(1, t1);
    TILE(0, 0);
    __syncthreads();
    // tile T+1 (buf1/set1); prefetch tile T+2 into buf0/set0
    STAGEA(0, 0, t2 * 128);
    STAGEA(0, 1, t2 * 128);
    LOADB(0, t2);
    TILE(1, 1);
    __syncthreads();
  }
#undef TILE
#undef GRP
#undef RD_A
#undef LOADB
#undef STAGEA

#pragma unroll
  for (int m = 0; m < 8; ++m)
#pragma unroll
    for (int n = 0; n < 4; ++n) {
      const size_t col = n0 + wc * 64 + n * 16 + c;
      const size_t rb = m0 + wr * 128 + m * 16 + g4 * 4;
      bool tovt = false;
      if constexpr (FUSEV) tovt = (col >= 4096);
      if (tovt) {
        const size_t cc = col - 4096;
        const size_t b = rb >> 11, s0 = rb & 2047;
        short4 o;
        o.x = f2bf(acc[m][n][0]); o.y = f2bf(acc[m][n][1]);
        o.z = f2bf(acc[m][n][2]); o.w = f2bf(acc[m][n][3]);
        *(short4*)&VT[(b * 2048 + cc) * 2048 + s0] = o;
      } else {
#pragma unroll
        for (int r = 0; r < 4; ++r) storeC(C, (rb + r) * (size_t)N + col, acc[m][n][r]);
      }
    }
}

// ---------------- RoPE in-place on K of qkv [B,S,6144] (Q is roped in attn) ----------------
__global__ __launch_bounds__(256) void rope_kernel(short* __restrict__ qkv) {
  const int g = blockIdx.x * 256 + threadIdx.x;  // 1,048,576 threads
  const int jg = g & 7;
  const int h = (g >> 3) & 15;
  const int bs = g >> 7;  // 0..8191
  const int s = bs & 2047;
  const size_t base = (size_t)bs * 6144 + 2048 + h * 128 + jg * 8;
  short8_t lo = *(short8_t*)&qkv[base];
  short8_t hi = *(short8_t*)&qkv[base + 64];
  short8_t olo, ohi;
#pragma unroll
  for (int t = 0; t < 8; ++t) {
    const int j = jg * 8 + t;
    const float inv = exp2f((float)j * -0.20762050593046f);  // log2(10000)/64
    float sn, cn;
    sincosf((float)s * inv, &sn, &cn);
    const float a = bf2f(lo[t]), b = bf2f(hi[t]);
    olo[t] = f2bf(a * cn - b * sn);
    ohi[t] = f2bf(b * cn + a * sn);
  }
  *(short8_t*)&qkv[base] = olo;
  *(short8_t*)&qkv[base + 64] = ohi;
}

// ---- causal flash attention, KVBLK=32 (r12/r15 exact: best measured attn config) ----
__global__ __launch_bounds__(256) void attn_kernel(const short* __restrict__ qkv,
                                                   const short* __restrict__ vt,
                                                   short* __restrict__ o) {
  __shared__ __align__(16) short Kl[2][32 * 128];   // 8 KB/buf: [key][d], swz (row&7)<<4
  __shared__ __align__(16) short Vl[2][128 * 32];   // 8 KB/buf: [d][key], swz (row&3)<<4
  __shared__ __align__(16) short Pl[4][16 * 40];    // per-wave P tile, padded stride 40
  const int tid = threadIdx.x, lane = tid & 63, w = tid >> 6;
  const int c = lane & 15, g4 = lane >> 4;
  const int blk = blockIdx.x;
  const int xcd = blk & 7;
  const int l = blk >> 3;              // 0..255
  const int bh = xcd * 8 + (l >> 5);   // 8 contiguous bh per XCD
  const int h = bh & 15, b = bh >> 4;
  const int q0 = (31 - (l & 31)) * 64; // heavy tiles dispatched first
  const int srow = q0 + w * 16 + c;

  // ---- load Q row, apply RoPE in-register ----
  short8_t qf[4];
  {
    const size_t qr = ((size_t)b * 2048 + srow) * 6144 + h * 128;
    float fl[4][8];
#pragma unroll
    for (int dc = 0; dc < 4; ++dc) {
      short8_t rawv = *(const short8_t*)&qkv[qr + dc * 32 + g4 * 8];
#pragma unroll
      for (int t = 0; t < 8; ++t) fl[dc][t] = bf2f(rawv[t]);
    }
#pragma unroll
    for (int pd = 0; pd < 2; ++pd)
#pragma unroll
      for (int t = 0; t < 8; ++t) {
        const int j = pd * 32 + g4 * 8 + t;
        const float inv = exp2f((float)j * -0.20762050593046f);
        float sn, cn;
        sincosf((float)srow * inv, &sn, &cn);
        const float a = fl[pd][t], bb = fl[pd + 2][t];
        fl[pd][t] = a * cn - bb * sn;
        fl[pd + 2][t] = bb * cn + a * sn;
      }
#pragma unroll
    for (int dc = 0; dc < 4; ++dc) {
      short8_t q8;
#pragma unroll
      for (int t = 0; t < 8; ++t) q8[t] = f2bf(fl[dc][t]);
      qf[dc] = q8;
    }
  }

  f32x4 acc_o[8] = {};
  float rs[4] = {0.f, 0.f, 0.f, 0.f};
  const float scale2 = 0.12751875222364685f;  // (1/sqrt(128)) * log2(e)
  const char* Kbase = (const char*)qkv + ((size_t)b * 2048 * 6144 + 2048 + h * 128) * 2;
  const char* Vbase = (const char*)vt + ((size_t)(b * 16 + h) * 128 * 2048) * 2;

  const char* kq[2];
  const char* vq[2];
#pragma unroll
  for (int i = 0; i < 2; ++i) {
    const int L = ((w * 2 + i) << 10) + lane * 16;
    {  // K tile: 32 rows x 256 B
      const int row = L >> 8, inner = L & 255;
      kq[i] = Kbase + (size_t)row * 12288 + (inner ^ ((row & 7) << 4));
    }
    {  // V tile: 128 rows x 64 B
      const int row = L >> 6, inner = L & 63;
      vq[i] = Vbase + (size_t)row * 4096 + (inner ^ ((row & 3) << 4));
    }
  }
  auto stage = [&](int buf, int kv0) {
#pragma unroll
    for (int i = 0; i < 2; ++i) {
      gld16(kq[i] + (size_t)kv0 * 12288, (char*)Kl + (buf << 13) + ((w * 2 + i) << 10));
      gld16(vq[i] + (size_t)kv0 * 2, (char*)Vl + (buf << 13) + ((w * 2 + i) << 10));
    }
  };

  stage(0, 0);
  __syncthreads();
  int cur = 0;
  const int kvend = q0 + 32;  // last tile covers keys [q0+32, q0+64)
  for (int kv0 = 0; kv0 <= kvend; kv0 += 32) {
    if (kv0 <= q0) stage(cur ^ 1, kv0 + 32);
    const char* Kb = (const char*)Kl + (cur << 13);
    const char* Vb = (const char*)Vl + (cur << 13);
    const bool diag = (kv0 >= q0);  // last two tiles need masking
    float p[2][4];
#pragma unroll
    for (int kt = 0; kt < 2; ++kt) {
      f32x4 s4 = {};
      const int krow = kt * 16 + c;
      __builtin_amdgcn_s_setprio(1);
#pragma unroll
      for (int dc = 0; dc < 4; ++dc) {
        const int inner = (dc * 64 + g4 * 16) ^ ((krow & 7) << 4);
        short8_t kf = *(const short8_t*)(Kb + krow * 256 + inner);
        s4 = __builtin_amdgcn_mfma_f32_16x16x32_bf16(qf[dc], kf, s4, 0, 0, 0);
      }
      __builtin_amdgcn_s_setprio(0);
#pragma unroll
      for (int r = 0; r < 4; ++r) {
        float v = s4[r] * scale2 - 8.0f;
        if (diag) {
          const int kc = kv0 + kt * 16 + c;
          const int qr2 = q0 + w * 16 + g4 * 4 + r;
          if (kc > qr2) v = -1e30f;  // exp2 -> 0
        }
        const float pe = exp2f(v);
        p[kt][r] = pe;
        rs[r] += pe;
      }
    }
    // pack P to bf16 via v_cvt_pk_bf16_f32
#pragma unroll
    for (int kt = 0; kt < 2; ++kt)
#pragma unroll
      for (int r = 0; r < 4; r += 2) {
        uint32_t pk;
        asm("v_cvt_pk_bf16_f32 %0, %1, %2" : "=v"(pk) : "v"(p[kt][r]), "v"(p[kt][r + 1]));
        Pl[w][(g4 * 4 + r) * 40 + kt * 16 + c] = (short)(pk & 0xffffu);
        Pl[w][(g4 * 4 + r + 1) * 40 + kt * 16 + c] = (short)(pk >> 16);
      }
    {
      short8_t pf = *(const short8_t*)&Pl[w][c * 40 + g4 * 8];
      __builtin_amdgcn_s_setprio(1);
#pragma unroll
      for (int dt = 0; dt < 8; ++dt) {
        const int vrow = dt * 16 + c;
        const int inner = (g4 * 16) ^ ((vrow & 3) << 4);
        short8_t vf = *(const short8_t*)(Vb + vrow * 64 + inner);
        acc_o[dt] = __builtin_amdgcn_mfma_f32_16x16x32_bf16(pf, vf, acc_o[dt], 0, 0, 0);
      }
      __builtin_amdgcn_s_setprio(0);
    }
    __syncthreads();  // drains staging vmcnt; next buffer ready
    cur ^= 1;
  }
#pragma unroll
  for (int off = 1; off < 16; off <<= 1)
#pragma unroll
    for (int r = 0; r < 4; ++r) rs[r] += __shfl_xor(rs[r], off);
  const size_t ob = ((size_t)b * 2048 + q0 + w * 16 + g4 * 4) * 2048 + h * 128;
#pragma unroll
  for (int dt = 0; dt < 8; ++dt)
#pragma unroll
    for (int r = 0; r < 4; ++r)
      o[ob + (size_t)r * 2048 + dt * 16 + c] = f2bf(acc_o[dt][r] / rs[r]);
}

extern "C" void kernel_launch(void* const* d_in, const int* in_sizes, int n_in,
                              void* d_out, int out_size, void* d_ws, size_t ws_size,
                              hipStream_t stream) {
  const float* x = (const float*)d_in[0];
  // d_in[1] = att_mask: exact causal -1e9 triu mask; implemented analytically.
  const float* Wqkv = (const float*)d_in[2];
  const float* Wout = (const float*)d_in[3];
  float* out = (float*)d_out;
  char* ws = (char*)d_ws;
  short* xb    = (short*)ws;                     // x bf16:    33,554,432
  short* wqb   = (short*)(ws + 33554432ull);     // Wqkv bf16: 25,165,824
  short* qkv   = (short*)(ws + 58720256ull);     // qkv bf16: 100,663,296
  short* vt    = (short*)(ws + 159383552ull);    // Vt bf16:   33,554,432
  short* woutb = (short*)(ws + 192937984ull);    // Wout bf16:  8,388,608
  short* attno = xb;   // reuse after GEMM1

  conv3_kernel<<<2048, 256, 0, stream>>>(x, Wqkv, Wout, xb, wqb, woutb);
  gemmrb<short, true><<<768, 512, 0, stream>>>(xb, wqb, qkv, vt, 8192, 6144, 2048);
  rope_kernel<<<4096, 256, 0, stream>>>(qkv);  // K only; Q roped inside attn
  attn_kernel<<<2048, 256, 0, stream>>>(qkv, vt, attno);
  gemmrb<float, false><<<256, 512, 0, stream>>>(attno, woutb, out, nullptr, 8192, 2048, 2048);
}

// Round 17
// 502.765 us; speedup vs baseline: 1.3162x; 1.3162x over previous
//
#include <hip/hip_runtime.h>
#include <stdint.h>

typedef __attribute__((ext_vector_type(8))) short short8_t;
typedef __attribute__((ext_vector_type(4))) float f32x4;

__device__ __forceinline__ short f2bf(float f) {
  union { float f; uint32_t u; } v; v.f = f;
  uint32_t r = v.u + 0x7FFFu + ((v.u >> 16) & 1u);
  return (short)(r >> 16);
}
__device__ __forceinline__ float bf2f(short s) {
  union { uint32_t u; float f; } v; v.u = ((uint32_t)(uint16_t)s) << 16; return v.f;
}
__device__ __forceinline__ void gld16(const void* g, void* l) {
  __builtin_amdgcn_global_load_lds((const __attribute__((address_space(1))) void*)g,
                                   (__attribute__((address_space(3))) void*)l, 16, 0, 0);
}

// ---------------- fused f32 -> bf16 convert of x, Wqkv, Wout ----------------
__global__ __launch_bounds__(256) void conv3_kernel(const float* __restrict__ x,
                                                    const float* __restrict__ wqkv,
                                                    const float* __restrict__ wout,
                                                    short* __restrict__ xb,
                                                    short* __restrict__ wqb,
                                                    short* __restrict__ woutb) {
  int i = blockIdx.x * 256 + threadIdx.x;
  const int stride = gridDim.x * 256;
  for (; i < 8388608; i += stride) {
    const float4* src;
    short4* dst;
    int j;
    if (i < 4194304) { src = (const float4*)x; dst = (short4*)xb; j = i; }
    else if (i < 7340032) { src = (const float4*)wqkv; dst = (short4*)wqb; j = i - 4194304; }
    else { src = (const float4*)wout; dst = (short4*)woutb; j = i - 7340032; }
    float4 v = src[j];
    short4 o;
    o.x = f2bf(v.x); o.y = f2bf(v.y); o.z = f2bf(v.z); o.w = f2bf(v.w);
    dst[j] = o;
  }
}

// ============ 256x256 8-phase GEMM (r9/r12/r15 frozen): C = A[M,K]*B[N,K]^T ============
__device__ __forceinline__ void storeC(float* C, size_t i, float v) { C[i] = v; }
__device__ __forceinline__ void storeC(short* C, size_t i, float v) { C[i] = f2bf(v); }

template <typename OT, bool FUSEV>
__global__ __launch_bounds__(512, 2) void gemm8p(const short* __restrict__ A,
                                                 const short* __restrict__ B,
                                                 OT* __restrict__ C,
                                                 short* __restrict__ VT,
                                                 int M, int N, int K) {
  __shared__ __align__(16) short lds[65536];
  const int tid = threadIdx.x, lane = tid & 63, w = tid >> 6;
  const int wr = w >> 2, wc = w & 3;
  const int c = lane & 15, g4 = lane >> 4;
  const int xcd = (int)blockIdx.x & 7;
  const int t = (int)blockIdx.x >> 3;
  const int bx = (t & 7) + 8 * (t >> 5);
  const int by = xcd * 4 + ((t >> 3) & 3);
  const size_t m0 = (size_t)by * 256, n0 = (size_t)bx * 256;
  const size_t Kb = (size_t)K * 2;
  const char* Ab = (const char*)A + m0 * Kb;
  const char* Bb = (const char*)B + n0 * Kb;
  const char* aq[2];
  const char* bq[2];
#pragma unroll
  for (int i = 0; i < 2; ++i) {
    const size_t ro = (size_t)((i * 8 + w) * 16 + c) * Kb + g4 * 16;
    aq[i] = Ab + ro;
    bq[i] = Bb + ro;
  }
  char* alds = (char*)lds;
  const int aoff = wr * 8192 + lane * 16;
  const int boff = 65536 + wc * 4096 + lane * 16;
  f32x4 acc[8][4] = {};
  const int NT = K >> 6, NIT = NT >> 1;

  short8_t af[2][4], bfr[2][4];

#define STAGE(q, srcoff, ldsbase)                                  \
  gld16((q)[0] + (srcoff), alds + (ldsbase) + (w << 10));          \
  gld16((q)[1] + (srcoff), alds + (ldsbase) + ((8 + w) << 10))

  STAGE(aq, 0, 0);
  STAGE(bq, 0, 65536);
  STAGE(aq, 64, 16384);
  STAGE(bq, 64, 81920);
  STAGE(aq, 128, 32768);
  STAGE(bq, 128, 98304);
  asm volatile("s_waitcnt vmcnt(0)" ::: "memory");
  asm volatile("s_barrier" ::: "memory");

#define RD_A(S, mi, OFF) \
  asm volatile("ds_read_b128 %0, %1 offset:%c2" : "=v"(af[S][mi]) : "v"(aoff), "i"(OFF))
#define RD_B(S, ni, OFF) \
  asm volatile("ds_read_b128 %0, %1 offset:%c2" : "=v"(bfr[S][ni]) : "v"(boff), "i"(OFF))

#define PREF_A(S, BSEL, KS, MQ)                           \
  RD_A(S, 0, (BSEL) + (KS)*16384 + ((MQ)*4 + 0) * 1024);  \
  RD_A(S, 1, (BSEL) + (KS)*16384 + ((MQ)*4 + 1) * 1024);  \
  RD_A(S, 2, (BSEL) + (KS)*16384 + ((MQ)*4 + 2) * 1024);  \
  RD_A(S, 3, (BSEL) + (KS)*16384 + ((MQ)*4 + 3) * 1024)

#define PREF_B(S, BSEL, KS)                  \
  RD_B(S, 0, (BSEL) + (KS)*16384 + 0);       \
  RD_B(S, 1, (BSEL) + (KS)*16384 + 1024);    \
  RD_B(S, 2, (BSEL) + (KS)*16384 + 2048);    \
  RD_B(S, 3, (BSEL) + (KS)*16384 + 3072)

#define MFMA16(AS, BS, MQ)                                                               \
  __builtin_amdgcn_s_setprio(1);                                                         \
  _Pragma("unroll") for (int mi = 0; mi < 4; ++mi) {                                     \
    _Pragma("unroll") for (int n = 0; n < 4; ++n)                                        \
      acc[(MQ)*4 + mi][n] = __builtin_amdgcn_mfma_f32_16x16x32_bf16(                     \
          af[AS][mi], bfr[BS][n], acc[(MQ)*4 + mi][n], 0, 0, 0);                         \
  }                                                                                      \
  __builtin_amdgcn_s_setprio(0)

#define PHASE_E(AS, BS, PBSEL, PKS, q, srcoff, sbase)              \
  PREF_A(AS ^ 1, PBSEL, PKS, 1);                                   \
  STAGE(q, srcoff, sbase);                                         \
  asm volatile("s_waitcnt lgkmcnt(4)" ::: "memory");               \
  __builtin_amdgcn_sched_barrier(0);                               \
  MFMA16(AS, BS, 0);                                               \
  asm volatile("s_barrier" ::: "memory")

#define PHASE_O(AS, BS, PBSEL, PKS, q, srcoff, sbase, GATE)        \
  PREF_B(BS ^ 1, PBSEL, PKS);                                      \
  PREF_A(AS ^ 1, PBSEL, PKS, 0);                                   \
  STAGE(q, srcoff, sbase);                                         \
  asm volatile("s_waitcnt lgkmcnt(8)" ::: "memory");               \
  __builtin_amdgcn_sched_barrier(0);                               \
  MFMA16(AS, BS, 1);                                               \
  GATE;                                                            \
  asm volatile("s_barrier" ::: "memory")

#define GATE8 asm volatile("s_waitcnt vmcnt(8)" ::: "memory")
#define GATE4 asm volatile("s_waitcnt vmcnt(4)" ::: "memory")
#define NOGATE (void)0

  PREF_B(0, 0, 0);
  PREF_A(0, 0, 0, 0);

  for (int it = 0; it < NIT; ++it) {
    const int T = it << 1;
    const int t1 = (T + 1) << 7;
    const int t2 = (T + 2 < NT ? T + 2 : NT - 1) << 7;
    const int t3 = (T + 3 < NT ? T + 3 : NT - 1) << 7;
    PHASE_E(0, 0, 0, 0,      aq, t1 + 64, 49152);
    PHASE_O(1, 0, 0, 1,      bq, t1 + 64, 114688, NOGATE);
    PHASE_E(0, 1, 0, 1,      aq, t2, 0);
    PHASE_O(1, 1, 32768, 0,  bq, t2, 65536, GATE8);
    PHASE_E(0, 0, 32768, 0,  aq, t2 + 64, 16384);
    PHASE_O(1, 0, 32768, 1,  bq, t2 + 64, 81920, NOGATE);
    PHASE_E(0, 1, 32768, 1,  aq, t3, 32768);
    PHASE_O(1, 1, 0, 0,      bq, t3, 98304, GATE4);
  }
#undef PHASE_E
#undef PHASE_O
#undef GATE8
#undef GATE4
#undef NOGATE
#undef MFMA16
#undef PREF_A
#undef PREF_B
#undef RD_A
#undef RD_B
#undef STAGE

#pragma unroll
  for (int m = 0; m < 8; ++m)
#pragma unroll
    for (int n = 0; n < 4; ++n) {
      const size_t col = n0 + wc * 64 + n * 16 + c;
      const size_t rb = m0 + wr * 128 + m * 16 + g4 * 4;
      bool tovt = false;
      if constexpr (FUSEV) tovt = (col >= 4096);
      if (tovt) {
        const size_t cc = col - 4096;
        const size_t b = rb >> 11, s0 = rb & 2047;
        short4 o;
        o.x = f2bf(acc[m][n][0]); o.y = f2bf(acc[m][n][1]);
        o.z = f2bf(acc[m][n][2]); o.w = f2bf(acc[m][n][3]);
        *(short4*)&VT[(b * 2048 + cc) * 2048 + s0] = o;
      } else {
#pragma unroll
        for (int r = 0; r < 4; ++r) storeC(C, (rb + r) * (size_t)N + col, acc[m][n][r]);
      }
    }
}

// ---------------- RoPE in-place on K of qkv [B,S,6144] (Q is roped in attn) ----------------
__global__ __launch_bounds__(256) void rope_kernel(short* __restrict__ qkv) {
  const int g = blockIdx.x * 256 + threadIdx.x;  // 1,048,576 threads
  const int jg = g & 7;
  const int h = (g >> 3) & 15;
  const int bs = g >> 7;  // 0..8191
  const int s = bs & 2047;
  const size_t base = (size_t)bs * 6144 + 2048 + h * 128 + jg * 8;
  short8_t lo = *(short8_t*)&qkv[base];
  short8_t hi = *(short8_t*)&qkv[base + 64];
  short8_t olo, ohi;
#pragma unroll
  for (int t = 0; t < 8; ++t) {
    const int j = jg * 8 + t;
    const float inv = exp2f((float)j * -0.20762050593046f);  // log2(10000)/64
    float sn, cn;
    sincosf((float)s * inv, &sn, &cn);
    const float a = bf2f(lo[t]), b = bf2f(hi[t]);
    olo[t] = f2bf(a * cn - b * sn);
    ohi[t] = f2bf(b * cn + a * sn);
  }
  *(short8_t*)&qkv[base] = olo;
  *(short8_t*)&qkv[base + 64] = ohi;
}

// ---- causal flash attention, KVBLK=32 (r12/r15 exact: best measured attn config) ----
__global__ __launch_bounds__(256) void attn_kernel(const short* __restrict__ qkv,
                                                   const short* __restrict__ vt,
                                                   short* __restrict__ o) {
  __shared__ __align__(16) short Kl[2][32 * 128];   // 8 KB/buf: [key][d], swz (row&7)<<4
  __shared__ __align__(16) short Vl[2][128 * 32];   // 8 KB/buf: [d][key], swz (row&3)<<4
  __shared__ __align__(16) short Pl[4][16 * 40];    // per-wave P tile, padded stride 40
  const int tid = threadIdx.x, lane = tid & 63, w = tid >> 6;
  const int c = lane & 15, g4 = lane >> 4;
  const int blk = blockIdx.x;
  const int xcd = blk & 7;
  const int l = blk >> 3;              // 0..255
  const int bh = xcd * 8 + (l >> 5);   // 8 contiguous bh per XCD
  const int h = bh & 15, b = bh >> 4;
  const int q0 = (31 - (l & 31)) * 64; // heavy tiles dispatched first
  const int srow = q0 + w * 16 + c;

  // ---- load Q row, apply RoPE in-register ----
  short8_t qf[4];
  {
    const size_t qr = ((size_t)b * 2048 + srow) * 6144 + h * 128;
    float fl[4][8];
#pragma unroll
    for (int dc = 0; dc < 4; ++dc) {
      short8_t rawv = *(const short8_t*)&qkv[qr + dc * 32 + g4 * 8];
#pragma unroll
      for (int t = 0; t < 8; ++t) fl[dc][t] = bf2f(rawv[t]);
    }
#pragma unroll
    for (int pd = 0; pd < 2; ++pd)
#pragma unroll
      for (int t = 0; t < 8; ++t) {
        const int j = pd * 32 + g4 * 8 + t;
        const float inv = exp2f((float)j * -0.20762050593046f);
        float sn, cn;
        sincosf((float)srow * inv, &sn, &cn);
        const float a = fl[pd][t], bb = fl[pd + 2][t];
        fl[pd][t] = a * cn - bb * sn;
        fl[pd + 2][t] = bb * cn + a * sn;
      }
#pragma unroll
    for (int dc = 0; dc < 4; ++dc) {
      short8_t q8;
#pragma unroll
      for (int t = 0; t < 8; ++t) q8[t] = f2bf(fl[dc][t]);
      qf[dc] = q8;
    }
  }

  f32x4 acc_o[8] = {};
  float rs[4] = {0.f, 0.f, 0.f, 0.f};
  const float scale2 = 0.12751875222364685f;  // (1/sqrt(128)) * log2(e)
  const char* Kbase = (const char*)qkv + ((size_t)b * 2048 * 6144 + 2048 + h * 128) * 2;
  const char* Vbase = (const char*)vt + ((size_t)(b * 16 + h) * 128 * 2048) * 2;

  const char* kq[2];
  const char* vq[2];
#pragma unroll
  for (int i = 0; i < 2; ++i) {
    const int L = ((w * 2 + i) << 10) + lane * 16;
    {  // K tile: 32 rows x 256 B
      const int row = L >> 8, inner = L & 255;
      kq[i] = Kbase + (size_t)row * 12288 + (inner ^ ((row & 7) << 4));
    }
    {  // V tile: 128 rows x 64 B
      const int row = L >> 6, inner = L & 63;
      vq[i] = Vbase + (size_t)row * 4096 + (inner ^ ((row & 3) << 4));
    }
  }
  auto stage = [&](int buf, int kv0) {
#pragma unroll
    for (int i = 0; i < 2; ++i) {
      gld16(kq[i] + (size_t)kv0 * 12288, (char*)Kl + (buf << 13) + ((w * 2 + i) << 10));
      gld16(vq[i] + (size_t)kv0 * 2, (char*)Vl + (buf << 13) + ((w * 2 + i) << 10));
    }
  };

  stage(0, 0);
  __syncthreads();
  int cur = 0;
  const int kvend = q0 + 32;  // last tile covers keys [q0+32, q0+64)
  for (int kv0 = 0; kv0 <= kvend; kv0 += 32) {
    if (kv0 <= q0) stage(cur ^ 1, kv0 + 32);
    const char* Kb = (const char*)Kl + (cur << 13);
    const char* Vb = (const char*)Vl + (cur << 13);
    const bool diag = (kv0 >= q0);  // last two tiles need masking
    float p[2][4];
#pragma unroll
    for (int kt = 0; kt < 2; ++kt) {
      f32x4 s4 = {};
      const int krow = kt * 16 + c;
      __builtin_amdgcn_s_setprio(1);
#pragma unroll
      for (int dc = 0; dc < 4; ++dc) {
        const int inner = (dc * 64 + g4 * 16) ^ ((krow & 7) << 4);
        short8_t kf = *(const short8_t*)(Kb + krow * 256 + inner);
        s4 = __builtin_amdgcn_mfma_f32_16x16x32_bf16(qf[dc], kf, s4, 0, 0, 0);
      }
      __builtin_amdgcn_s_setprio(0);
#pragma unroll
      for (int r = 0; r < 4; ++r) {
        float v = s4[r] * scale2 - 8.0f;
        if (diag) {
          const int kc = kv0 + kt * 16 + c;
          const int qr2 = q0 + w * 16 + g4 * 4 + r;
          if (kc > qr2) v = -1e30f;  // exp2 -> 0
        }
        const float pe = exp2f(v);
        p[kt][r] = pe;
        rs[r] += pe;
      }
    }
    // pack P to bf16 via v_cvt_pk_bf16_f32
#pragma unroll
    for (int kt = 0; kt < 2; ++kt)
#pragma unroll
      for (int r = 0; r < 4; r += 2) {
        uint32_t pk;
        asm("v_cvt_pk_bf16_f32 %0, %1, %2" : "=v"(pk) : "v"(p[kt][r]), "v"(p[kt][r + 1]));
        Pl[w][(g4 * 4 + r) * 40 + kt * 16 + c] = (short)(pk & 0xffffu);
        Pl[w][(g4 * 4 + r + 1) * 40 + kt * 16 + c] = (short)(pk >> 16);
      }
    {
      short8_t pf = *(const short8_t*)&Pl[w][c * 40 + g4 * 8];
      __builtin_amdgcn_s_setprio(1);
#pragma unroll
      for (int dt = 0; dt < 8; ++dt) {
        const int vrow = dt * 16 + c;
        const int inner = (g4 * 16) ^ ((vrow & 3) << 4);
        short8_t vf = *(const short8_t*)(Vb + vrow * 64 + inner);
        acc_o[dt] = __builtin_amdgcn_mfma_f32_16x16x32_bf16(pf, vf, acc_o[dt], 0, 0, 0);
      }
      __builtin_amdgcn_s_setprio(0);
    }
    __syncthreads();  // drains staging vmcnt; next buffer ready
    cur ^= 1;
  }
#pragma unroll
  for (int off = 1; off < 16; off <<= 1)
#pragma unroll
    for (int r = 0; r < 4; ++r) rs[r] += __shfl_xor(rs[r], off);
  const size_t ob = ((size_t)b * 2048 + q0 + w * 16 + g4 * 4) * 2048 + h * 128;
#pragma unroll
  for (int dt = 0; dt < 8; ++dt)
#pragma unroll
    for (int r = 0; r < 4; ++r)
      o[ob + (size_t)r * 2048 + dt * 16 + c] = f2bf(acc_o[dt][r] / rs[r]);
}

extern "C" void kernel_launch(void* const* d_in, const int* in_sizes, int n_in,
                              void* d_out, int out_size, void* d_ws, size_t ws_size,
                              hipStream_t stream) {
  const float* x = (const float*)d_in[0];
  // d_in[1] = att_mask: exact causal -1e9 triu mask; implemented analytically.
  const float* Wqkv = (const float*)d_in[2];
  const float* Wout = (const float*)d_in[3];
  float* out = (float*)d_out;
  char* ws = (char*)d_ws;
  short* xb    = (short*)ws;                     // x bf16:    33,554,432
  short* wqb   = (short*)(ws + 33554432ull);     // Wqkv bf16: 25,165,824
  short* qkv   = (short*)(ws + 58720256ull);     // qkv bf16: 100,663,296
  short* vt    = (short*)(ws + 159383552ull);    // Vt bf16:   33,554,432
  short* woutb = (short*)(ws + 192937984ull);    // Wout bf16:  8,388,608
  short* attno = xb;   // reuse after GEMM1

  conv3_kernel<<<2048, 256, 0, stream>>>(x, Wqkv, Wout, xb, wqb, woutb);
  gemm8p<short, true><<<768, 512, 0, stream>>>(xb, wqb, qkv, vt, 8192, 6144, 2048);
  rope_kernel<<<4096, 256, 0, stream>>>(qkv);  // K only; Q roped inside attn
  attn_kernel<<<2048, 256, 0, stream>>>(qkv, vt, attno);
  gemm8p<float, false><<<256, 512, 0, stream>>>(attno, woutb, out, nullptr, 8192, 2048, 2048);
}